// Round 1
// baseline (137.237 us; speedup 1.0000x reference)
//
#include <hip/hip_runtime.h>
#include <hip/hip_bf16.h>

// Problem constants
#define CCH   256        // channels C
#define NG    16         // groups
#define GCN   16         // group channels
#define CRD   64         // reduced channels C/R
#define HH    56
#define WWD   56
#define HWP   3136       // 56*56
#define BB    8
#define NPIX  25088      // B*H*W
#define PADW  62         // 56 + 2*3
#define PADHW 3844       // 62*62
#define K2    49
#define O2N   784        // K2 * NG
#define EPSV  1e-5f

// workspace layout (in floats)
#define XP_OFF   0
#define XP_SZ    (BB*CCH*PADHW)            // 7,872,512 floats
#define Y_OFF    (XP_OFF + XP_SZ)
#define Y_SZ     (CRD*NPIX)                // 1,605,632
#define W1T_OFF  (Y_OFF + Y_SZ)
#define W1T_SZ   (CCH*CRD)                 // 16,384
#define W2T_OFF  (W1T_OFF + W1T_SZ)
#define W2T_SZ   (CRD*O2N)                 // 50,176
#define WGT_FOFF (W2T_OFF + W2T_SZ)        // bf16 array lives here (39.3 MB)
// total ~77.5 MB of ws

// ---------------------------------------------------------------------------
// prep: zero-pad x into xp, transpose W1 -> W1T[c][o], W2 -> W2T[c][o2]
// ---------------------------------------------------------------------------
__global__ __launch_bounds__(256) void prep_kernel(const float* __restrict__ x,
                                                   const float* __restrict__ W1,
                                                   const float* __restrict__ W2,
                                                   float* __restrict__ ws) {
    int gid0 = blockIdx.x * 256 + threadIdx.x;
    int stride = gridDim.x * 256;
    float* xp = ws + XP_OFF;
    for (int e = gid0; e < XP_SZ; e += stride) {
        int col = e % PADW;
        int row = (e / PADW) % PADW;
        int bc  = e / PADHW;          // b*256 + c
        int sr = row - 3, sc = col - 3;
        float v = 0.f;
        if ((unsigned)sr < (unsigned)HH && (unsigned)sc < (unsigned)WWD)
            v = x[bc * HWP + sr * WWD + sc];
        xp[e] = v;
    }
    if (gid0 < W1T_SZ) {            // W1T[c*64+o] = W1[o*256+c]
        int c = gid0 >> 6, o = gid0 & 63;
        ws[W1T_OFF + gid0] = W1[o * CCH + c];
    }
    if (gid0 < W2T_SZ) {            // W2T[c*784+o2] = W2[o2*64+c]
        int c = gid0 / O2N, o2 = gid0 % O2N;
        ws[W2T_OFF + gid0] = W2[o2 * CRD + c];
    }
}

// ---------------------------------------------------------------------------
// conv1 + BN(eval) + ReLU:  y[o][P] = relu(BN(sum_c x[b,c,hw]*W1[o,c] + b1[o]))
// block: 64 pixels x 4 o-quarters (256 thr). W1T staged in LDS in 2 halves.
// ---------------------------------------------------------------------------
__global__ __launch_bounds__(256) void conv1_kernel(const float* __restrict__ x,
                                                    const float* __restrict__ b1,
                                                    const float* __restrict__ gamma,
                                                    const float* __restrict__ beta,
                                                    const float* __restrict__ mean,
                                                    const float* __restrict__ var,
                                                    float* __restrict__ ws) {
    __shared__ float w1t[128 * CRD];   // 32 KB: half the channels at a time
    int tid  = threadIdx.x;
    int lane = tid & 63;
    int oq   = tid >> 6;               // 0..3 -> outputs oq*16 .. +15
    int p0 = blockIdx.x * 64;
    int p  = p0 + lane;
    int b  = p0 / HWP;                 // uniform per block (3136 % 64 == 0)
    int hw = p - b * HWP;
    const float* xb = x + (b * CCH) * HWP + hw;

    float acc[16];
#pragma unroll
    for (int j = 0; j < 16; ++j) acc[j] = 0.f;

    for (int half = 0; half < 2; ++half) {
        int c0 = half * 128;
        __syncthreads();
        for (int i = tid; i < 128 * CRD; i += 256)
            w1t[i] = ws[W1T_OFF + c0 * CRD + i];
        __syncthreads();
#pragma unroll 4
        for (int cl = 0; cl < 128; ++cl) {
            float xv = xb[(c0 + cl) * HWP];
            const float4* wr = reinterpret_cast<const float4*>(&w1t[cl * CRD + oq * 16]);
#pragma unroll
            for (int j4 = 0; j4 < 4; ++j4) {
                float4 wv = wr[j4];
                acc[j4*4+0] = fmaf(xv, wv.x, acc[j4*4+0]);
                acc[j4*4+1] = fmaf(xv, wv.y, acc[j4*4+1]);
                acc[j4*4+2] = fmaf(xv, wv.z, acc[j4*4+2]);
                acc[j4*4+3] = fmaf(xv, wv.w, acc[j4*4+3]);
            }
        }
    }

    int ob = oq * 16;
#pragma unroll
    for (int j = 0; j < 16; ++j) {
        int o = ob + j;
        float s = gamma[o] * rsqrtf(var[o] + EPSV);
        float v = (acc[j] + b1[o] - mean[o]) * s + beta[o];
        v = fmaxf(v, 0.f);
        ws[Y_OFF + o * NPIX + p] = v;
    }
}

// ---------------------------------------------------------------------------
// conv2: wgt[b, o2, hw] = sum_c y[c][P]*W2[o2,c] + b2[o2]   (stored bf16)
// grid: (pixel tiles of 64) x (49 o2-tiles of 16). 4 outputs/thread.
// ---------------------------------------------------------------------------
__global__ __launch_bounds__(256) void conv2_kernel(const float* __restrict__ ws,
                                                    const float* __restrict__ b2,
                                                    __hip_bfloat16* __restrict__ wgt) {
    __shared__ float w2t[CRD * 16];    // 4 KB  [c][o2i]
    int tid = threadIdx.x;
    int o2base = blockIdx.y * 16;
    for (int i = tid; i < CRD * 16; i += 256) {
        int c = i >> 4, oi = i & 15;
        w2t[i] = ws[W2T_OFF + c * O2N + o2base + oi];
    }
    __syncthreads();

    int lane = tid & 63, oq = tid >> 6;
    int p = blockIdx.x * 64 + lane;
    const float* y = ws + Y_OFF + p;

    float a0 = 0.f, a1 = 0.f, a2 = 0.f, a3 = 0.f;
#pragma unroll 8
    for (int c = 0; c < CRD; ++c) {
        float yv = y[c * NPIX];
        float4 wv = *reinterpret_cast<const float4*>(&w2t[c * 16 + oq * 4]);
        a0 = fmaf(yv, wv.x, a0);
        a1 = fmaf(yv, wv.y, a1);
        a2 = fmaf(yv, wv.z, a2);
        a3 = fmaf(yv, wv.w, a3);
    }

    int b  = p / HWP;                  // uniform per block
    int hw = p - b * HWP;
    float acc[4] = {a0, a1, a2, a3};
#pragma unroll
    for (int j = 0; j < 4; ++j) {
        int o2 = o2base + oq * 4 + j;
        float v = acc[j] + b2[o2];
        wgt[(b * O2N + o2) * HWP + hw] = __float2bfloat16(v);
    }
}

// ---------------------------------------------------------------------------
// involution: out[b, g*16+ch, h, w] = sum_k xp[b, g*16+ch, h+ki, w+kj] * wgt[b,g,k,h,w]
// block: (b, g, 4 rows). thread: (w lane, 4-channel quad). wgt tile in LDS [k][r][w].
// ---------------------------------------------------------------------------
__global__ __launch_bounds__(256) void invol_kernel(const float* __restrict__ ws,
                                                    const __hip_bfloat16* __restrict__ wgt,
                                                    float* __restrict__ out) {
    __shared__ float wl[K2 * 4 * WWD]; // 49*4*56 floats = 43.9 KB
    int h0 = blockIdx.x * 4;
    int g  = blockIdx.y;
    int b  = blockIdx.z;
    int tid = threadIdx.x;

    // stage wgt tile (bf16 -> f32)
    const __hip_bfloat16* wg = wgt + (b * O2N + g * K2) * HWP + h0 * WWD;
    for (int i = tid; i < K2 * 4 * WWD; i += 256) {
        int k = i / 224;               // 224 = 4*56
        int rem = i - k * 224;         // r*56 + w
        wl[i] = __bfloat162float(wg[k * HWP + rem]);
    }
    __syncthreads();

    int w  = tid & 63;
    int cq = tid >> 6;                 // channel quad 0..3
    if (w >= WWD) return;

    const float* xpb = ws + XP_OFF + (b * CCH + g * GCN + cq * 4) * PADHW + h0 * PADW + w;

    float acc[4][4];                   // [c][r]
#pragma unroll
    for (int c = 0; c < 4; ++c)
#pragma unroll
        for (int r = 0; r < 4; ++r) acc[c][r] = 0.f;

#pragma unroll
    for (int xr = 0; xr < 10; ++xr) {  // padded input rows h0 .. h0+9
        float xv[4][8];
#pragma unroll
        for (int c = 0; c < 4; ++c) {
            const float* row = xpb + c * PADHW + xr * PADW;
#pragma unroll
            for (int d = 0; d < 8; ++d) xv[c][d] = row[d];
        }
#pragma unroll
        for (int ki = 0; ki < 7; ++ki) {
            int r = xr - ki;           // compile-time after full unroll
            if (r >= 0 && r < 4) {
#pragma unroll
                for (int dj = 0; dj < 7; ++dj) {
                    float wv = wl[((ki * 7 + dj) * 4 + r) * WWD + w];
#pragma unroll
                    for (int c = 0; c < 4; ++c)
                        acc[c][r] = fmaf(xv[c][dj], wv, acc[c][r]);
                }
            }
        }
    }

#pragma unroll
    for (int c = 0; c < 4; ++c)
#pragma unroll
        for (int r = 0; r < 4; ++r)
            out[(b * CCH + g * GCN + cq * 4 + c) * HWP + (h0 + r) * WWD + w] = acc[c][r];
}

// ---------------------------------------------------------------------------
extern "C" void kernel_launch(void* const* d_in, const int* in_sizes, int n_in,
                              void* d_out, int out_size, void* d_ws, size_t ws_size,
                              hipStream_t stream) {
    const float* x     = (const float*)d_in[0];
    const float* W1    = (const float*)d_in[1];
    const float* b1    = (const float*)d_in[2];
    const float* gamma = (const float*)d_in[3];
    const float* beta  = (const float*)d_in[4];
    const float* mean  = (const float*)d_in[5];
    const float* var   = (const float*)d_in[6];
    const float* W2    = (const float*)d_in[7];
    const float* b2    = (const float*)d_in[8];

    float* ws  = (float*)d_ws;
    float* out = (float*)d_out;
    __hip_bfloat16* wgt = (__hip_bfloat16*)(ws + WGT_FOFF);

    prep_kernel<<<4096, 256, 0, stream>>>(x, W1, W2, ws);
    conv1_kernel<<<NPIX / 64, 256, 0, stream>>>(x, b1, gamma, beta, mean, var, ws);
    conv2_kernel<<<dim3(NPIX / 64, O2N / 16), 256, 0, stream>>>(ws, b2, wgt);
    invol_kernel<<<dim3(HH / 4, NG, BB), 256, 0, stream>>>(ws, wgt, out);
}

// Round 2
// 94.721 us; speedup vs baseline: 1.4488x; 1.4488x over previous
//
#include <hip/hip_runtime.h>
#include <hip/hip_bf16.h>

// Problem constants
#define CCH   256        // channels C
#define NG    16         // groups
#define GCN   16         // group channels
#define CRD   64         // reduced channels C/R
#define HH    56
#define WWD   56
#define HWP   3136       // 56*56
#define BB    8
#define NPIX  25088      // B*H*W
#define PADW  62         // 56 + 2*3
#define PADHW 3844       // 62*62
#define K2    49
#define O2N   784        // K2 * NG
#define EPSV  1e-5f

typedef unsigned short ushort_t;
typedef __attribute__((ext_vector_type(8))) short bf16x8;
typedef __attribute__((ext_vector_type(4))) float f32x4;

// workspace layout (float units)
// xp (fp32 padded x) | x_t bf16 (overlaid later by wgt bf16) | y_t bf16 | W1b | W2b | bn
#define XP_OFF   0
#define XP_SZ    7872512                  // 8*256*3844 floats
#define XW_OFF   7872512                  // x_t: 25088*256 shorts; wgt: 25088*784 shorts
#define YT_OFF   17707008                 // XW_OFF + 784*25088/2
#define W1B_OFF  18509824                 // YT_OFF + 25088*64/2
#define W2B_OFF  18518016                 // + 16384/2
#define BNS_OFF  18543104                 // + 50176/2
#define BNT_OFF  18543168                 // + 64
// end = 18543232 floats = 74.2 MB

__device__ __forceinline__ ushort_t f2bf(float f) {
    unsigned u = __builtin_bit_cast(unsigned, f);
    return (ushort_t)((u + 0x7FFFu + ((u >> 16) & 1u)) >> 16);   // RNE
}

// ---------------------------------------------------------------------------
// prep: zero-pad x into xp; W1,W2 -> bf16; fold BN+bias into scale/shift
// ---------------------------------------------------------------------------
__global__ __launch_bounds__(256) void prep_kernel(const float* __restrict__ x,
                                                   const float* __restrict__ W1,
                                                   const float* __restrict__ b1,
                                                   const float* __restrict__ gamma,
                                                   const float* __restrict__ beta,
                                                   const float* __restrict__ mean,
                                                   const float* __restrict__ var,
                                                   const float* __restrict__ W2,
                                                   float* __restrict__ ws) {
    int gid0 = blockIdx.x * 256 + threadIdx.x;
    int stride = gridDim.x * 256;
    float* xp = ws + XP_OFF;
    for (int e = gid0; e < XP_SZ; e += stride) {
        int col = e % PADW;
        int row = (e / PADW) % PADW;
        int bc  = e / PADHW;
        int sr = row - 3, sc = col - 3;
        float v = 0.f;
        if ((unsigned)sr < (unsigned)HH && (unsigned)sc < (unsigned)WWD)
            v = x[bc * HWP + sr * WWD + sc];
        xp[e] = v;
    }
    ushort_t* w1b = (ushort_t*)(ws + W1B_OFF);
    if (gid0 < CRD * CCH) w1b[gid0] = f2bf(W1[gid0]);          // [o][c] row-major
    ushort_t* w2b = (ushort_t*)(ws + W2B_OFF);
    if (gid0 < O2N * CRD) w2b[gid0] = f2bf(W2[gid0]);          // [o2][c] row-major
    if (gid0 < CRD) {
        float s = gamma[gid0] * rsqrtf(var[gid0] + EPSV);
        ws[BNS_OFF + gid0] = s;
        ws[BNT_OFF + gid0] = (b1[gid0] - mean[gid0]) * s + beta[gid0];
    }
}

// ---------------------------------------------------------------------------
// pack_x: transpose x (B,C,H,W) -> x_t[pix][256] bf16 via LDS (64 hw x 256 c tile)
// ---------------------------------------------------------------------------
__global__ __launch_bounds__(256) void pack_x(const float* __restrict__ x,
                                              float* __restrict__ ws) {
    __shared__ ushort_t st[64 * 270];      // pad 256->270 shorts (odd-word row stride)
    int tid = threadIdx.x;
    int b = blockIdx.y, hw0 = blockIdx.x * 64;
    int lane = tid & 63, c4 = tid >> 6;
    const float* xb = x + (b * CCH) * HWP + hw0 + lane;
#pragma unroll 8
    for (int i = 0; i < 64; ++i) {
        int c = i * 4 + c4;
        st[lane * 270 + c] = f2bf(xb[c * HWP]);
    }
    __syncthreads();
    const unsigned* stu = (const unsigned*)st;           // row stride 135 words
    unsigned* xtu = (unsigned*)(ws + XW_OFF);            // x_t rows: 128 words
    int rowg = b * HWP + hw0;
#pragma unroll
    for (int k = 0; k < 32; ++k) {
        int idx = k * 256 + tid;
        int row = idx >> 7, c2 = idx & 127;
        xtu[(rowg + row) * 128 + c2] = stu[row * 135 + c2];
    }
}

// ---------------------------------------------------------------------------
// conv1 (MFMA bf16): y_t[pix][64] = relu(bns[o]*(x_t @ W1^T)[o][pix] + bnt[o])
// grid (4 o-tiles, 196 pix-tiles of 128). wave: 16 o x 32 pix, K=256 (8 ksteps)
// ---------------------------------------------------------------------------
__global__ __launch_bounds__(256) void conv1_mfma(float* __restrict__ ws) {
    const ushort_t* xt  = (const ushort_t*)(ws + XW_OFF);
    const ushort_t* w1b = (const ushort_t*)(ws + W1B_OFF);
    const float* bns = ws + BNS_OFF;
    const float* bnt = ws + BNT_OFF;
    ushort_t* yt = (ushort_t*)(ws + YT_OFF);

    int tid = threadIdx.x, lane = tid & 63, wv = tid >> 6;
    int lr = lane & 15, lg = lane >> 4;
    int ot = blockIdx.x;                                  // 0..3
    int pixbase = blockIdx.y * 128 + wv * 32;

    const bf16x8* ap = (const bf16x8*)(w1b + (ot * 16 + lr) * CCH + lg * 8);
    bf16x8 a[8];
#pragma unroll
    for (int ks = 0; ks < 8; ++ks) a[ks] = ap[ks * 4];    // kstep = 32 shorts = 4 units

    f32x4 acc[2] = {{0.f,0.f,0.f,0.f}, {0.f,0.f,0.f,0.f}};
#pragma unroll
    for (int f = 0; f < 2; ++f) {
        const bf16x8* bp = (const bf16x8*)(xt + (pixbase + f * 16 + lr) * CCH + lg * 8);
#pragma unroll
        for (int ks = 0; ks < 8; ++ks)
            acc[f] = __builtin_amdgcn_mfma_f32_16x16x32_bf16(a[ks], bp[ks * 4], acc[f], 0, 0, 0);
    }

    int o0 = ot * 16 + lg * 4;
    float4 s4 = *(const float4*)(bns + o0);
    float4 t4 = *(const float4*)(bnt + o0);
#pragma unroll
    for (int f = 0; f < 2; ++f) {
        int pix = pixbase + f * 16 + lr;
        union { ushort_t u[4]; uint2 v; } pk;
        pk.u[0] = f2bf(fmaxf(acc[f][0] * s4.x + t4.x, 0.f));
        pk.u[1] = f2bf(fmaxf(acc[f][1] * s4.y + t4.y, 0.f));
        pk.u[2] = f2bf(fmaxf(acc[f][2] * s4.z + t4.z, 0.f));
        pk.u[3] = f2bf(fmaxf(acc[f][3] * s4.w + t4.w, 0.f));
        *(uint2*)(yt + pix * CRD + o0) = pk.v;
    }
}

// ---------------------------------------------------------------------------
// conv2 (MFMA bf16): wgt[o2][pix] bf16 = (W2 @ y)[o2][pix] + b2[o2]
// grid (98 pix-tiles of 256, 49 o2-tiles). wave: 16 o2 x 64 pix, K=64 (2 ksteps)
// ---------------------------------------------------------------------------
__global__ __launch_bounds__(256) void conv2_mfma(const float* __restrict__ b2,
                                                  float* __restrict__ ws) {
    const ushort_t* yt  = (const ushort_t*)(ws + YT_OFF);
    const ushort_t* w2b = (const ushort_t*)(ws + W2B_OFF);
    ushort_t* wgt = (ushort_t*)(ws + XW_OFF);             // overlays dead x_t

    int tid = threadIdx.x, lane = tid & 63, wv = tid >> 6;
    int lr = lane & 15, lg = lane >> 4;
    int o2base = blockIdx.y * 16;
    int pixbase = blockIdx.x * 256 + wv * 64;

    const bf16x8* ap = (const bf16x8*)(w2b + (o2base + lr) * CRD + lg * 8);
    bf16x8 a0 = ap[0], a1 = ap[4];

    f32x4 acc[4] = {{0.f,0.f,0.f,0.f},{0.f,0.f,0.f,0.f},{0.f,0.f,0.f,0.f},{0.f,0.f,0.f,0.f}};
#pragma unroll
    for (int f = 0; f < 4; ++f) {
        const bf16x8* bp = (const bf16x8*)(yt + (pixbase + f * 16 + lr) * CRD + lg * 8);
        acc[f] = __builtin_amdgcn_mfma_f32_16x16x32_bf16(a0, bp[0], acc[f], 0, 0, 0);
        acc[f] = __builtin_amdgcn_mfma_f32_16x16x32_bf16(a1, bp[4], acc[f], 0, 0, 0);
    }

    int r0 = lg * 4;
    float4 b2v = *(const float4*)(b2 + o2base + r0);
    float b2a[4] = {b2v.x, b2v.y, b2v.z, b2v.w};
#pragma unroll
    for (int f = 0; f < 4; ++f) {
        unsigned pix = (unsigned)(pixbase + f * 16 + lr);
        unsigned b  = pix / 3136u;
        unsigned hw = pix - b * 3136u;
        ushort_t* wp = wgt + ((b * O2N + o2base + r0) * HWP + hw);
#pragma unroll
        for (int j = 0; j < 4; ++j)
            wp[j * HWP] = f2bf(acc[f][j] + b2a[j]);
    }
}

// ---------------------------------------------------------------------------
// involution: out[b, g*16+ch, h, w] = sum_k xp[b, ch, h+ki, w+kj] * wgt[b,g,k,h,w]
// ---------------------------------------------------------------------------
__global__ __launch_bounds__(256) void invol_kernel(const float* __restrict__ ws,
                                                    const __hip_bfloat16* __restrict__ wgt,
                                                    float* __restrict__ out) {
    __shared__ float wl[K2 * 4 * WWD];
    int h0 = blockIdx.x * 4;
    int g  = blockIdx.y;
    int b  = blockIdx.z;
    int tid = threadIdx.x;

    const __hip_bfloat16* wg = wgt + (b * O2N + g * K2) * HWP + h0 * WWD;
    for (int i = tid; i < K2 * 4 * WWD; i += 256) {
        int k = i / 224;
        int rem = i - k * 224;
        wl[i] = __bfloat162float(wg[k * HWP + rem]);
    }
    __syncthreads();

    int w  = tid & 63;
    int cq = tid >> 6;
    if (w >= WWD) return;

    const float* xpb = ws + XP_OFF + (b * CCH + g * GCN + cq * 4) * PADHW + h0 * PADW + w;

    float acc[4][4];
#pragma unroll
    for (int c = 0; c < 4; ++c)
#pragma unroll
        for (int r = 0; r < 4; ++r) acc[c][r] = 0.f;

#pragma unroll
    for (int xr = 0; xr < 10; ++xr) {
        float xv[4][8];
#pragma unroll
        for (int c = 0; c < 4; ++c) {
            const float* row = xpb + c * PADHW + xr * PADW;
#pragma unroll
            for (int d = 0; d < 8; ++d) xv[c][d] = row[d];
        }
#pragma unroll
        for (int ki = 0; ki < 7; ++ki) {
            int r = xr - ki;
            if (r >= 0 && r < 4) {
#pragma unroll
                for (int dj = 0; dj < 7; ++dj) {
                    float wv = wl[((ki * 7 + dj) * 4 + r) * WWD + w];
#pragma unroll
                    for (int c = 0; c < 4; ++c)
                        acc[c][r] = fmaf(xv[c][dj], wv, acc[c][r]);
                }
            }
        }
    }

#pragma unroll
    for (int c = 0; c < 4; ++c)
#pragma unroll
        for (int r = 0; r < 4; ++r)
            out[(b * CCH + g * GCN + cq * 4 + c) * HWP + (h0 + r) * WWD + w] = acc[c][r];
}

// ---------------------------------------------------------------------------
extern "C" void kernel_launch(void* const* d_in, const int* in_sizes, int n_in,
                              void* d_out, int out_size, void* d_ws, size_t ws_size,
                              hipStream_t stream) {
    const float* x     = (const float*)d_in[0];
    const float* W1    = (const float*)d_in[1];
    const float* b1    = (const float*)d_in[2];
    const float* gamma = (const float*)d_in[3];
    const float* beta  = (const float*)d_in[4];
    const float* mean  = (const float*)d_in[5];
    const float* var   = (const float*)d_in[6];
    const float* W2    = (const float*)d_in[7];
    const float* b2    = (const float*)d_in[8];

    float* ws  = (float*)d_ws;
    float* out = (float*)d_out;

    prep_kernel<<<4096, 256, 0, stream>>>(x, W1, b1, gamma, beta, mean, var, W2, ws);
    pack_x<<<dim3(HWP / 64, BB), 256, 0, stream>>>(x, ws);
    conv1_mfma<<<dim3(4, NPIX / 128), 256, 0, stream>>>(ws);
    conv2_mfma<<<dim3(NPIX / 256, K2), 256, 0, stream>>>(b2, ws);
    invol_kernel<<<dim3(HH / 4, NG, BB), 256, 0, stream>>>(
        ws, (const __hip_bfloat16*)(ws + XW_OFF), out);
}